// Round 11
// baseline (1222.752 us; speedup 1.0000x reference)
//
#include <hip/hip_runtime.h>

#define NPG 57       // nodes per graph
#define NEPG 160     // edges per graph
#define NB 80        // branches per graph
#define HID 128
#define NG 4096      // graphs
#define NL 5

typedef __attribute__((ext_vector_type(8))) _Float16 f16x8;
typedef __attribute__((ext_vector_type(4))) _Float16 f16x4;
typedef __attribute__((ext_vector_type(4))) float f32x4;

#define MFMA16(A, B, C) __builtin_amdgcn_mfma_f32_16x16x32_f16(A, B, C, 0, 0, 0)

__device__ __forceinline__ f16x8 ldf8(const _Float16* base, int byteoff) {
    return *(const f16x8*)((const char*)base + byteoff);
}

// ---- weight prep: fp16 hi/lo split, n-major; element offsets as prior rounds ----
// wb fp16: [0..229375] conv(5)+P+Q hi/lo pairs (mat*32768 + {0|16384} + n*128+k)
//          [229376..231423] phys hi [16][128]; [231424..233471] phys lo
__global__ void prep(const float* __restrict__ convW, const float* __restrict__ mlpW1,
                     const float* __restrict__ physW1, const float* __restrict__ convb,
                     const float* __restrict__ bn_gamma, const float* __restrict__ bn_beta,
                     const float* __restrict__ bn_mean, const float* __restrict__ bn_var,
                     _Float16* __restrict__ wb, float* __restrict__ fsc,
                     float* __restrict__ fsh) {
    int id = blockIdx.x * 256 + threadIdx.x;
    if (id < 114688) {
        int mat = id >> 14, rem = id & 16383, n = rem >> 7, k = rem & 127;
        float w;
        if (mat < 5)       w = convW[mat * 16384 + k * 128 + n];
        else if (mat == 5) w = mlpW1[k * 128 + n];
        else               w = mlpW1[(128 + k) * 128 + n];
        _Float16 hi = (_Float16)w;
        wb[mat * 32768 + n * 128 + k] = hi;
        wb[mat * 32768 + 16384 + n * 128 + k] = (_Float16)(w - (float)hi);
    } else if (id < 116736) {
        int p = id - 114688, n = p >> 7, k = p & 127;
        float w = physW1[k * 16 + n];
        _Float16 hi = (_Float16)w;
        wb[229376 + p] = hi;
        wb[231424 + p] = (_Float16)(w - (float)hi);
    } else if (id < 117376) {
        int p = id - 116736;
        float sc = bn_gamma[p] * rsqrtf(bn_var[p] + 1e-5f);
        fsc[p] = sc;
        fsh[p] = fmaf(convb[p] - bn_mean[p], sc, bn_beta[p]);
    }
}

// 512 threads = 8 waves: wave = (r-tile wv&3) x (c-half wv>>2).
// fp16 hi/lo SEPARATE native arrays -> frag loads are direct ds_read_b128, zero unpack.
// A (dense agg matrix) register-resident across all 5 layers. 68KB LDS -> 2 blocks/CU.
__global__ __launch_bounds__(512, 2) void pinn_fused(
    const float* __restrict__ x, const int* __restrict__ edge_index,
    const int* __restrict__ branch_u, const int* __restrict__ branch_v,
    const float* __restrict__ Wp, const float* __restrict__ bp,
    const float* __restrict__ physb1, const float* __restrict__ physW2,
    const float* __restrict__ physb2,
    const float* __restrict__ mlpW1, const float* __restrict__ mlpb1,
    const float* __restrict__ mlpW2, const float* __restrict__ mlpb2,
    const _Float16* __restrict__ wb, const float* __restrict__ fsc,
    const float* __restrict__ fsh, float* __restrict__ out) {
    __shared__ _Float16 hTh[128 * 64];   // h^T hi, swz byte=(s*2)^((c&7)<<4)
    __shared__ _Float16 hTl[128 * 64];   // h^T lo
    __shared__ _Float16 mh[64 * 128];    // m hi (also: A-f32 staging / final hrow hi)
    __shared__ _Float16 ml[64 * 128];    // m lo (also: Ah/Al fp16 / final hrow lo)
    __shared__ float dinv[64];
    __shared__ int   deg[64];
    __shared__ short esrc[NEPG], edst[NEPG];
    __shared__ float theta[64];
    __shared__ float red[NB];
    __shared__ int   bu[NB], bv[NB];

    const int g = blockIdx.x;
    const int tid = threadIdx.x;
    const int lane = tid & 63;
    const int wv = tid >> 6;            // 0..7
    const int ln15 = lane & 15;
    const int hi4 = lane >> 4;          // 0..3
    const int R0 = 16 * (wv & 3);       // row-tile base
    const int ct0 = 4 * (wv >> 2);      // c-half base tile (0 or 4)

    float* Af = (float*)mh;             // 64x64 f32 staging (aliases mh, setup only)
    _Float16* Ah = ml;                  // 64x64 fp16 swz (aliases ml, setup only)
    _Float16* Al = ml + 4096;

    // ---- setup: projection -> hT, zero A, init ----
    {
        int c = tid & 127;
        int sw = (c & 7) << 4;
        float w0 = Wp[c], w1 = Wp[HID + c], w2 = Wp[2 * HID + c], w3 = Wp[3 * HID + c];
        float bb = bp[c];
        for (int r = tid >> 7; r < 64; r += 4) {
            float h0 = 0.f;
            if (r < NPG) {
                float4 xv = ((const float4*)x)[g * NPG + r];
                h0 = fmaf(xv.x, w0, fmaf(xv.y, w1, fmaf(xv.z, w2, fmaf(xv.w, w3, bb))));
            }
            _Float16 hh = (_Float16)h0;
            *(_Float16*)((char*)(hTh + c * 64) + ((r * 2) ^ sw)) = hh;
            *(_Float16*)((char*)(hTl + c * 64) + ((r * 2) ^ sw)) = (_Float16)(h0 - (float)hh);
        }
    }
    for (int i = tid; i < 4096; i += 512) Af[i] = 0.f;
    if (tid < 64) deg[tid] = (tid < NPG) ? 1 : 0;     // self-loop
    if (tid < NB) { bu[tid] = branch_u[tid]; bv[tid] = branch_v[tid]; red[tid] = 0.f; }
    __syncthreads();

    if (tid < NEPG) {
        int gs = edge_index[g * NEPG + tid];
        int gd = edge_index[NG * NEPG + g * NEPG + tid];
        esrc[tid] = (short)(gs - g * NPG);
        edst[tid] = (short)(gd - g * NPG);
        atomicAdd(&deg[edst[tid]], 1);
    }
    __syncthreads();
    if (tid < 64) dinv[tid] = (tid < NPG) ? rsqrtf((float)deg[tid]) : 0.f;
    __syncthreads();
    if (tid < NEPG) {
        int s = esrc[tid], d = edst[tid];
        atomicAdd(&Af[d * 64 + s], dinv[s] * dinv[d]);
    }
    if (tid < NPG) atomicAdd(&Af[tid * 64 + tid], dinv[tid] * dinv[tid]);
    __syncthreads();
    for (int i = tid; i < 4096; i += 512) {            // A f32 -> fp16 hi/lo (swz)
        int r = i >> 6, s = i & 63;
        float v = Af[i];
        _Float16 hi = (_Float16)v;
        int byteoff = (s * 2) ^ ((r & 7) << 4);
        *(_Float16*)((char*)(Ah + r * 64) + byteoff) = hi;
        *(_Float16*)((char*)(Al + r * 64) + byteoff) = (_Float16)(v - (float)hi);
    }
    __syncthreads();

    // A-fragments register-resident for all layers (rows R0+ln15, k=s)
    f16x8 Ahf[2], Alf[2];
    {
        int ar = R0 + ln15;
        int swr = (ar & 7) << 4;
        Ahf[0] = ldf8(Ah + ar * 64, ((8 * hi4) * 2) ^ swr);
        Ahf[1] = ldf8(Ah + ar * 64, ((32 + 8 * hi4) * 2) ^ swr);
        Alf[0] = ldf8(Al + ar * 64, ((8 * hi4) * 2) ^ swr);
        Alf[1] = ldf8(Al + ar * 64, ((32 + 8 * hi4) * 2) ^ swr);
    }
    __syncthreads();   // Ah/Al (ml region) dead -> mh/ml free for layers

    const int mrow = R0 + ln15;
    const int swm = (mrow & 7) << 4;

    // ---- 5 layers: MFMA1 (m=A@h) -> MFMA2 (z=m@W) -> BN/ReLU/residual ----
    for (int l = 0; l < NL; ++l) {
        f32x4 macc[4];
#pragma unroll
        for (int j = 0; j < 4; ++j) macc[j] = (f32x4){0.f, 0.f, 0.f, 0.f};
#pragma unroll
        for (int ks2 = 0; ks2 < 2; ++ks2) {
#pragma unroll
            for (int j = 0; j < 4; ++j) {
                int c = 16 * (ct0 + j) + ln15;
                int byteoff = ((32 * ks2 + 8 * hi4) * 2) ^ ((c & 7) << 4);
                f16x8 hh = ldf8(hTh + c * 64, byteoff);
                f16x8 hl = ldf8(hTl + c * 64, byteoff);
                f32x4 a = macc[j];
                a = MFMA16(Ahf[ks2], hh, a);
                a = MFMA16(Ahf[ks2], hl, a);
                a = MFMA16(Alf[ks2], hh, a);
                macc[j] = a;
            }
        }
#pragma unroll
        for (int j = 0; j < 4; ++j) {                  // write m hi/lo (swz by row)
            int c = 16 * (ct0 + j) + ln15;
#pragma unroll
            for (int q = 0; q < 4; ++q) {
                int r = R0 + 4 * hi4 + q;
                float v = macc[j][q];
                _Float16 vh = (_Float16)v;
                int byteoff = (c * 2) ^ ((r & 7) << 4);
                *(_Float16*)((char*)(mh + r * 128) + byteoff) = vh;
                *(_Float16*)((char*)(ml + r * 128) + byteoff) = (_Float16)(v - (float)vh);
            }
        }
        __syncthreads();

        const _Float16* whi = wb + 2 * l * 16384;
        const _Float16* wlo = wb + (2 * l + 1) * 16384;
        f32x4 zacc[4];
#pragma unroll
        for (int j = 0; j < 4; ++j) zacc[j] = (f32x4){0.f, 0.f, 0.f, 0.f};
#pragma unroll
        for (int ks = 0; ks < 4; ++ks) {
            int byteoff = ((32 * ks + 8 * hi4) * 2) ^ swm;
            f16x8 mhf = ldf8(mh + mrow * 128, byteoff);
            f16x8 mlf = ldf8(ml + mrow * 128, byteoff);
#pragma unroll
            for (int j = 0; j < 4; ++j) {
                int n = 16 * (ct0 + j) + ln15;
                f16x8 bh = *(const f16x8*)(whi + n * 128 + 32 * ks + 8 * hi4);
                f16x8 bl = *(const f16x8*)(wlo + n * 128 + 32 * ks + 8 * hi4);
                f32x4 a = zacc[j];
                a = MFMA16(mhf, bh, a);
                a = MFMA16(mhf, bl, a);
                a = MFMA16(mlf, bh, a);
                zacc[j] = a;
            }
        }

        if (l < NL - 1) {
            // epilogue -> hT (each (c, r-block) uniquely owned; b64 vector ops)
#pragma unroll
            for (int j = 0; j < 4; ++j) {
                int c = 16 * (ct0 + j) + ln15;
                float scv = fsc[l * HID + c], shv = fsh[l * HID + c];
                int byteoff = ((R0 + 4 * hi4) * 2) ^ ((c & 7) << 4);
                f16x4 rh = *(const f16x4*)((const char*)(hTh + c * 64) + byteoff);
                f16x4 rl = *(const f16x4*)((const char*)(hTl + c * 64) + byteoff);
                f16x4 nh, nl;
#pragma unroll
                for (int q = 0; q < 4; ++q) {
                    float hold = (float)rh[q] + (float)rl[q];
                    float hnew = fmaxf(fmaf(zacc[j][q], scv, shv), 0.f) + hold;
                    _Float16 vh = (_Float16)hnew;
                    nh[q] = vh;
                    nl[q] = (_Float16)(hnew - (float)vh);
                }
                *(f16x4*)((char*)(hTh + c * 64) + byteoff) = nh;
                *(f16x4*)((char*)(hTl + c * 64) + byteoff) = nl;
            }
            __syncthreads();
        } else {
            __syncthreads();   // drain all MFMA2 m-reads before hrow overwrites m
            // final epilogue -> hrow (mh/ml region), row-major swz
#pragma unroll
            for (int j = 0; j < 4; ++j) {
                int c = 16 * (ct0 + j) + ln15;
                float scv = fsc[l * HID + c], shv = fsh[l * HID + c];
                int tbyte = ((R0 + 4 * hi4) * 2) ^ ((c & 7) << 4);
                f16x4 rh = *(const f16x4*)((const char*)(hTh + c * 64) + tbyte);
                f16x4 rl = *(const f16x4*)((const char*)(hTl + c * 64) + tbyte);
#pragma unroll
                for (int q = 0; q < 4; ++q) {
                    int r = R0 + 4 * hi4 + q;
                    float hold = (float)rh[q] + (float)rl[q];
                    float hnew = fmaxf(fmaf(zacc[j][q], scv, shv), 0.f) + hold;
                    _Float16 vh = (_Float16)hnew;
                    int byteoff = (c * 2) ^ ((r & 7) << 4);
                    *(_Float16*)((char*)(mh + r * 128) + byteoff) = vh;
                    *(_Float16*)((char*)(ml + r * 128) + byteoff) = (_Float16)(hnew - (float)vh);
                }
            }
            __syncthreads();
        }
    }
    // mh/ml now hold final h row-major (hi/lo)

    // ---- theta via MFMA (waves 0-3) ----
    if (wv < 4) {
        f32x4 t4 = (f32x4){0.f, 0.f, 0.f, 0.f};
        int r = 16 * wv + ln15;
        int swr = (r & 7) << 4;
#pragma unroll
        for (int ks = 0; ks < 4; ++ks) {
            int byteoff = ((32 * ks + 8 * hi4) * 2) ^ swr;
            f16x8 fh = ldf8(mh + r * 128, byteoff);
            f16x8 fl = ldf8(ml + r * 128, byteoff);
            f16x8 bh = *(const f16x8*)(wb + 229376 + ln15 * 128 + 32 * ks + 8 * hi4);
            f16x8 bl = *(const f16x8*)(wb + 231424 + ln15 * 128 + 32 * ks + 8 * hi4);
            t4 = MFMA16(fh, bh, t4);
            t4 = MFMA16(fh, bl, t4);
            t4 = MFMA16(fl, bh, t4);
        }
        float b1 = physb1[ln15], w2 = physW2[ln15], b2 = physb2[0];
#pragma unroll
        for (int q = 0; q < 4; ++q) {
            float val = fmaxf(t4[q] + b1, 0.f) * w2;
#pragma unroll
            for (int o = 1; o < 16; o <<= 1) val += __shfl_xor(val, o, 16);
            int rq = 16 * wv + 4 * hi4 + q;
            if (ln15 == 0 && rq < NPG) theta[rq] = val + b2;
        }
    }
    __syncthreads();

    // ---- branch-direct edge MLP: 10 (branch-tile x c-half) tasks over 8 waves ----
    for (int task = wv; task < 10; task += 8) {
        int t = task >> 1;
        int cb = 4 * (task & 1);
        int b = 16 * t + ln15;
        int ru = bu[b], rv = bv[b];
        f32x4 acc4[4];
#pragma unroll
        for (int j = 0; j < 4; ++j) acc4[j] = (f32x4){0.f, 0.f, 0.f, 0.f};
        const _Float16* ph = wb + 10 * 16384;
        const _Float16* pl = wb + 11 * 16384;
        const _Float16* qh = wb + 12 * 16384;
        const _Float16* ql = wb + 13 * 16384;
#pragma unroll
        for (int ks = 0; ks < 4; ++ks) {
            int ko = 32 * ks + 8 * hi4;
            f16x8 uh = ldf8(mh + ru * 128, ((ko * 2) ^ ((ru & 7) << 4)));
            f16x8 ul = ldf8(ml + ru * 128, ((ko * 2) ^ ((ru & 7) << 4)));
#pragma unroll
            for (int j = 0; j < 4; ++j) {
                int n = 16 * (cb + j) + ln15;
                f16x8 bh = *(const f16x8*)(ph + n * 128 + ko);
                f16x8 bl = *(const f16x8*)(pl + n * 128 + ko);
                f32x4 a = acc4[j];
                a = MFMA16(uh, bh, a);
                a = MFMA16(uh, bl, a);
                a = MFMA16(ul, bh, a);
                acc4[j] = a;
            }
            f16x8 vh = ldf8(mh + rv * 128, ((ko * 2) ^ ((rv & 7) << 4)));
            f16x8 vl = ldf8(ml + rv * 128, ((ko * 2) ^ ((rv & 7) << 4)));
#pragma unroll
            for (int j = 0; j < 4; ++j) {
                int n = 16 * (cb + j) + ln15;
                f16x8 bh = *(const f16x8*)(qh + n * 128 + ko);
                f16x8 bl = *(const f16x8*)(ql + n * 128 + ko);
                f32x4 a = acc4[j];
                a = MFMA16(vh, bh, a);
                a = MFMA16(vh, bl, a);
                a = MFMA16(vl, bh, a);
                acc4[j] = a;
            }
        }
        float dth[4];
#pragma unroll
        for (int q = 0; q < 4; ++q) {
            int bb = 16 * t + 4 * hi4 + q;
            dth[q] = theta[bu[bb]] - theta[bv[bb]];
        }
        float sums[4] = {0.f, 0.f, 0.f, 0.f};
#pragma unroll
        for (int j = 0; j < 4; ++j) {
            int ch = 16 * (cb + j) + ln15;
            float w256 = mlpW1[256 * HID + ch];
            float b1 = mlpb1[ch];
            float w2 = mlpW2[ch];
#pragma unroll
            for (int q = 0; q < 4; ++q)
                sums[q] += fmaxf(fmaf(dth[q], w256, acc4[j][q] + b1), 0.f) * w2;
        }
#pragma unroll
        for (int q = 0; q < 4; ++q) {
#pragma unroll
            for (int o = 1; o < 16; o <<= 1) sums[q] += __shfl_xor(sums[q], o, 16);
            if (ln15 == 0) atomicAdd(&red[16 * t + 4 * hi4 + q], sums[q]);
        }
    }
    __syncthreads();
    if (tid < NB) out[g * NB + tid] = red[tid] + mlpb2[0];
}

extern "C" void kernel_launch(void* const* d_in, const int* in_sizes, int n_in,
                              void* d_out, int out_size, void* d_ws, size_t ws_size,
                              hipStream_t stream) {
    const float* x          = (const float*)d_in[0];
    const int*   edge_index = (const int*)d_in[1];
    const int*   branch_u   = (const int*)d_in[2];
    const int*   branch_v   = (const int*)d_in[3];
    const float* Wp         = (const float*)d_in[4];
    const float* bp         = (const float*)d_in[5];
    const float* convW      = (const float*)d_in[6];
    const float* convb      = (const float*)d_in[7];
    const float* bn_gamma   = (const float*)d_in[8];
    const float* bn_beta    = (const float*)d_in[9];
    const float* bn_mean    = (const float*)d_in[10];
    const float* bn_var     = (const float*)d_in[11];
    const float* physW1     = (const float*)d_in[12];
    const float* physb1     = (const float*)d_in[13];
    const float* physW2     = (const float*)d_in[14];
    const float* physb2     = (const float*)d_in[15];
    const float* mlpW1      = (const float*)d_in[16];
    const float* mlpb1      = (const float*)d_in[17];
    const float* mlpW2      = (const float*)d_in[18];
    const float* mlpb2      = (const float*)d_in[19];
    float* out = (float*)d_out;

    _Float16* wb = (_Float16*)d_ws;                    // 466944 B
    float* fsc = (float*)((char*)d_ws + 466944);       // 5*128 floats
    float* fsh = fsc + 640;

    prep<<<459, 256, 0, stream>>>(convW, mlpW1, physW1, convb,
                                  bn_gamma, bn_beta, bn_mean, bn_var, wb, fsc, fsh);
    pinn_fused<<<NG, 512, 0, stream>>>(
        x, edge_index, branch_u, branch_v, Wp, bp,
        physb1, physW2, physb2, mlpW1, mlpb1, mlpW2, mlpb2,
        wb, fsc, fsh, out);
}

// Round 12
// 1184.787 us; speedup vs baseline: 1.0320x; 1.0320x over previous
//
#include <hip/hip_runtime.h>

#define NPG 57       // nodes per graph
#define NEPG 160     // edges per graph
#define NB 80        // branches per graph
#define HID 128
#define NG 4096      // graphs
#define NL 5

typedef __attribute__((ext_vector_type(8))) _Float16 f16x8;
typedef __attribute__((ext_vector_type(4))) _Float16 f16x4;
typedef __attribute__((ext_vector_type(4))) float f32x4;

#define MFMA16(A, B, C) __builtin_amdgcn_mfma_f32_16x16x32_f16(A, B, C, 0, 0, 0)

__device__ __forceinline__ f16x8 ldf8(const _Float16* base, int byteoff) {
    return *(const f16x8*)((const char*)base + byteoff);
}

// ---- weight prep: fp16 hi/lo split, n-major ----
// wb fp16: [0..229375] conv(5)+P+Q hi/lo pairs (mat*32768 + {0|16384} + n*128+k)
//          [229376..231423] phys hi [16][128]; [231424..233471] phys lo
__global__ void prep(const float* __restrict__ convW, const float* __restrict__ mlpW1,
                     const float* __restrict__ physW1, const float* __restrict__ convb,
                     const float* __restrict__ bn_gamma, const float* __restrict__ bn_beta,
                     const float* __restrict__ bn_mean, const float* __restrict__ bn_var,
                     _Float16* __restrict__ wb, float* __restrict__ fsc,
                     float* __restrict__ fsh) {
    int id = blockIdx.x * 256 + threadIdx.x;
    if (id < 114688) {
        int mat = id >> 14, rem = id & 16383, n = rem >> 7, k = rem & 127;
        float w;
        if (mat < 5)       w = convW[mat * 16384 + k * 128 + n];
        else if (mat == 5) w = mlpW1[k * 128 + n];
        else               w = mlpW1[(128 + k) * 128 + n];
        _Float16 hi = (_Float16)w;
        wb[mat * 32768 + n * 128 + k] = hi;
        wb[mat * 32768 + 16384 + n * 128 + k] = (_Float16)(w - (float)hi);
    } else if (id < 116736) {
        int p = id - 114688, n = p >> 7, k = p & 127;
        float w = physW1[k * 16 + n];
        _Float16 hi = (_Float16)w;
        wb[229376 + p] = hi;
        wb[231424 + p] = (_Float16)(w - (float)hi);
    } else if (id < 117376) {
        int p = id - 116736;
        float sc = bn_gamma[p] * rsqrtf(bn_var[p] + 1e-5f);
        fsc[p] = sc;
        fsh[p] = fmaf(convb[p] - bn_mean[p], sc, bn_beta[p]);
    }
}

// LDS diet vs R11: m single-fp16 (m-lo dropped; z = mh*(Wh+Wl)), A-frags converted
// once directly from f32 staging (no Ah/Al arrays), final h-lo reuses hTl region.
// 50.3KB -> 2 blocks/CU at 128KB-usable (3 if 160KB) => cross-graph overlap hides
// barrier drains (the R9-R11 invariant: duration tracks resident blocks/CU).
__global__ __launch_bounds__(512, 2) void pinn_fused(
    const float* __restrict__ x, const int* __restrict__ edge_index,
    const int* __restrict__ branch_u, const int* __restrict__ branch_v,
    const float* __restrict__ Wp, const float* __restrict__ bp,
    const float* __restrict__ physb1, const float* __restrict__ physW2,
    const float* __restrict__ physb2,
    const float* __restrict__ mlpW1, const float* __restrict__ mlpb1,
    const float* __restrict__ mlpW2, const float* __restrict__ mlpb2,
    const _Float16* __restrict__ wb, const float* __restrict__ fsc,
    const float* __restrict__ fsh, float* __restrict__ out) {
    __shared__ _Float16 hTh[128 * 64];   // h^T hi, swz byte=(s*2)^((c&7)<<4)
    __shared__ _Float16 hTl[128 * 64];   // h^T lo; later: final hrow-lo [64][128]
    __shared__ _Float16 mh[64 * 128];    // m (single fp16); setup: A f32 staging; final hrow-hi
    __shared__ float dinv[64];
    __shared__ int   deg[64];
    __shared__ short esrc[NEPG], edst[NEPG];
    __shared__ float theta[64];
    __shared__ float red[NB];
    __shared__ int   bu[NB], bv[NB];

    const int g = blockIdx.x;
    const int tid = threadIdx.x;
    const int lane = tid & 63;
    const int wv = tid >> 6;            // 0..7
    const int ln15 = lane & 15;
    const int hi4 = lane >> 4;          // 0..3
    const int R0 = 16 * (wv & 3);       // row-tile base
    const int ct0 = 4 * (wv >> 2);      // c-half base tile (0 or 4)

    float* Af = (float*)mh;             // 64x64 f32 A staging (aliases mh; setup only)
    _Float16* hrl = hTl;                // final h-lo row-major (reuses hTl region)

    // ---- setup: projection -> hT, zero A, init ----
    {
        int c = tid & 127;
        int sw = (c & 7) << 4;
        float w0 = Wp[c], w1 = Wp[HID + c], w2 = Wp[2 * HID + c], w3 = Wp[3 * HID + c];
        float bb = bp[c];
        for (int r = tid >> 7; r < 64; r += 4) {
            float h0 = 0.f;
            if (r < NPG) {
                float4 xv = ((const float4*)x)[g * NPG + r];
                h0 = fmaf(xv.x, w0, fmaf(xv.y, w1, fmaf(xv.z, w2, fmaf(xv.w, w3, bb))));
            }
            _Float16 hh = (_Float16)h0;
            *(_Float16*)((char*)(hTh + c * 64) + ((r * 2) ^ sw)) = hh;
            *(_Float16*)((char*)(hTl + c * 64) + ((r * 2) ^ sw)) = (_Float16)(h0 - (float)hh);
        }
    }
    for (int i = tid; i < 4096; i += 512) Af[i] = 0.f;
    if (tid < 64) deg[tid] = (tid < NPG) ? 1 : 0;     // self-loop
    if (tid < NB) { bu[tid] = branch_u[tid]; bv[tid] = branch_v[tid]; red[tid] = 0.f; }
    __syncthreads();

    if (tid < NEPG) {
        int gs = edge_index[g * NEPG + tid];
        int gd = edge_index[NG * NEPG + g * NEPG + tid];
        esrc[tid] = (short)(gs - g * NPG);
        edst[tid] = (short)(gd - g * NPG);
        atomicAdd(&deg[edst[tid]], 1);
    }
    __syncthreads();
    if (tid < 64) dinv[tid] = (tid < NPG) ? rsqrtf((float)deg[tid]) : 0.f;
    __syncthreads();
    if (tid < NEPG) {
        int s = esrc[tid], d = edst[tid];
        atomicAdd(&Af[d * 64 + s], dinv[s] * dinv[d]);
    }
    if (tid < NPG) atomicAdd(&Af[tid * 64 + tid], dinv[tid] * dinv[tid]);
    __syncthreads();

    // A-fragments from f32 staging -> registers, once, for all 5 layers
    f16x8 Ahf[2], Alf[2];
    {
        int ar = R0 + ln15;
#define CVTE(V, I, FH, FL) { _Float16 t_ = (_Float16)(V); FH[I] = t_; FL[I] = (_Float16)((V) - (float)t_); }
#pragma unroll
        for (int ks2 = 0; ks2 < 2; ++ks2) {
            const float* ap = &Af[ar * 64 + 32 * ks2 + 8 * hi4];
            float4 a0 = *(const float4*)ap;
            float4 a1 = *(const float4*)(ap + 4);
            f16x8 fh, fl;
            CVTE(a0.x, 0, fh, fl) CVTE(a0.y, 1, fh, fl)
            CVTE(a0.z, 2, fh, fl) CVTE(a0.w, 3, fh, fl)
            CVTE(a1.x, 4, fh, fl) CVTE(a1.y, 5, fh, fl)
            CVTE(a1.z, 6, fh, fl) CVTE(a1.w, 7, fh, fl)
            Ahf[ks2] = fh;
            Alf[ks2] = fl;
        }
#undef CVTE
    }
    __syncthreads();   // Af dead -> mh region free for m

    const int mrow = R0 + ln15;
    const int swm = (mrow & 7) << 4;

    // ---- 5 layers: MFMA1 (m=A@h) -> MFMA2 (z=m@W) -> BN/ReLU/residual ----
    for (int l = 0; l < NL; ++l) {
        f32x4 macc[4];
#pragma unroll
        for (int j = 0; j < 4; ++j) macc[j] = (f32x4){0.f, 0.f, 0.f, 0.f};
#pragma unroll
        for (int ks2 = 0; ks2 < 2; ++ks2) {
#pragma unroll
            for (int j = 0; j < 4; ++j) {
                int c = 16 * (ct0 + j) + ln15;
                int byteoff = ((32 * ks2 + 8 * hi4) * 2) ^ ((c & 7) << 4);
                f16x8 hh = ldf8(hTh + c * 64, byteoff);
                f16x8 hl = ldf8(hTl + c * 64, byteoff);
                f32x4 a = macc[j];
                a = MFMA16(Ahf[ks2], hh, a);
                a = MFMA16(Ahf[ks2], hl, a);
                a = MFMA16(Alf[ks2], hh, a);
                macc[j] = a;
            }
        }
#pragma unroll
        for (int j = 0; j < 4; ++j) {                  // write m (single fp16, swz by row)
            int c = 16 * (ct0 + j) + ln15;
#pragma unroll
            for (int q = 0; q < 4; ++q) {
                int r = R0 + 4 * hi4 + q;
                *(_Float16*)((char*)(mh + r * 128) + ((c * 2) ^ ((r & 7) << 4))) =
                    (_Float16)macc[j][q];
            }
        }
        __syncthreads();

        const _Float16* whi = wb + 2 * l * 16384;
        const _Float16* wlo = wb + (2 * l + 1) * 16384;
        f32x4 zacc[4];
#pragma unroll
        for (int j = 0; j < 4; ++j) zacc[j] = (f32x4){0.f, 0.f, 0.f, 0.f};
#pragma unroll
        for (int ks = 0; ks < 4; ++ks) {
            int byteoff = ((32 * ks + 8 * hi4) * 2) ^ swm;
            f16x8 mhf = ldf8(mh + mrow * 128, byteoff);
#pragma unroll
            for (int j = 0; j < 4; ++j) {
                int n = 16 * (ct0 + j) + ln15;
                f16x8 bh = *(const f16x8*)(whi + n * 128 + 32 * ks + 8 * hi4);
                f16x8 bl = *(const f16x8*)(wlo + n * 128 + 32 * ks + 8 * hi4);
                f32x4 a = zacc[j];
                a = MFMA16(mhf, bh, a);
                a = MFMA16(mhf, bl, a);
                zacc[j] = a;
            }
        }

        if (l < NL - 1) {
            // epilogue -> hT (each (c, r-block) uniquely owned; b64 vector ops)
#pragma unroll
            for (int j = 0; j < 4; ++j) {
                int c = 16 * (ct0 + j) + ln15;
                float scv = fsc[l * HID + c], shv = fsh[l * HID + c];
                int byteoff = ((R0 + 4 * hi4) * 2) ^ ((c & 7) << 4);
                f16x4 rh = *(const f16x4*)((const char*)(hTh + c * 64) + byteoff);
                f16x4 rl = *(const f16x4*)((const char*)(hTl + c * 64) + byteoff);
                f16x4 nh, nl;
#pragma unroll
                for (int q = 0; q < 4; ++q) {
                    float hold = (float)rh[q] + (float)rl[q];
                    float hnew = fmaxf(fmaf(zacc[j][q], scv, shv), 0.f) + hold;
                    _Float16 vh = (_Float16)hnew;
                    nh[q] = vh;
                    nl[q] = (_Float16)(hnew - (float)vh);
                }
                *(f16x4*)((char*)(hTh + c * 64) + byteoff) = nh;
                *(f16x4*)((char*)(hTl + c * 64) + byteoff) = nl;
            }
            __syncthreads();
        } else {
            // final layer: compute hnew in regs, barrier (drain m-reads + residual
            // reads), then write row-major hi->mh, lo->hTl-region (hrl)
            f32x4 hn[4];
#pragma unroll
            for (int j = 0; j < 4; ++j) {
                int c = 16 * (ct0 + j) + ln15;
                float scv = fsc[l * HID + c], shv = fsh[l * HID + c];
                int byteoff = ((R0 + 4 * hi4) * 2) ^ ((c & 7) << 4);
                f16x4 rh = *(const f16x4*)((const char*)(hTh + c * 64) + byteoff);
                f16x4 rl = *(const f16x4*)((const char*)(hTl + c * 64) + byteoff);
                f32x4 t;
#pragma unroll
                for (int q = 0; q < 4; ++q) {
                    float hold = (float)rh[q] + (float)rl[q];
                    t[q] = fmaxf(fmaf(zacc[j][q], scv, shv), 0.f) + hold;
                }
                hn[j] = t;
            }
            __syncthreads();
#pragma unroll
            for (int j = 0; j < 4; ++j) {
                int c = 16 * (ct0 + j) + ln15;
#pragma unroll
                for (int q = 0; q < 4; ++q) {
                    int r = R0 + 4 * hi4 + q;
                    float v = hn[j][q];
                    _Float16 vh = (_Float16)v;
                    int byteoff = (c * 2) ^ ((r & 7) << 4);
                    *(_Float16*)((char*)(mh + r * 128) + byteoff) = vh;
                    *(_Float16*)((char*)(hrl + r * 128) + byteoff) = (_Float16)(v - (float)vh);
                }
            }
            __syncthreads();
        }
    }
    // mh = final h-hi (row-major), hrl = final h-lo (row-major)

    // ---- theta via MFMA (waves 0-3) ----
    if (wv < 4) {
        f32x4 t4 = (f32x4){0.f, 0.f, 0.f, 0.f};
        int r = 16 * wv + ln15;
        int swr = (r & 7) << 4;
#pragma unroll
        for (int ks = 0; ks < 4; ++ks) {
            int byteoff = ((32 * ks + 8 * hi4) * 2) ^ swr;
            f16x8 fh = ldf8(mh + r * 128, byteoff);
            f16x8 fl = ldf8(hrl + r * 128, byteoff);
            f16x8 bh = *(const f16x8*)(wb + 229376 + ln15 * 128 + 32 * ks + 8 * hi4);
            f16x8 bl = *(const f16x8*)(wb + 231424 + ln15 * 128 + 32 * ks + 8 * hi4);
            t4 = MFMA16(fh, bh, t4);
            t4 = MFMA16(fh, bl, t4);
            t4 = MFMA16(fl, bh, t4);
        }
        float b1 = physb1[ln15], w2 = physW2[ln15], b2 = physb2[0];
#pragma unroll
        for (int q = 0; q < 4; ++q) {
            float val = fmaxf(t4[q] + b1, 0.f) * w2;
#pragma unroll
            for (int o = 1; o < 16; o <<= 1) val += __shfl_xor(val, o, 16);
            int rq = 16 * wv + 4 * hi4 + q;
            if (ln15 == 0 && rq < NPG) theta[rq] = val + b2;
        }
    }
    __syncthreads();

    // ---- branch-direct edge MLP: 10 (branch-tile x c-half) tasks over 8 waves ----
    for (int task = wv; task < 10; task += 8) {
        int t = task >> 1;
        int cb = 4 * (task & 1);
        int b = 16 * t + ln15;
        int ru = bu[b], rv = bv[b];
        f32x4 acc4[4];
#pragma unroll
        for (int j = 0; j < 4; ++j) acc4[j] = (f32x4){0.f, 0.f, 0.f, 0.f};
        const _Float16* ph = wb + 10 * 16384;
        const _Float16* pl = wb + 11 * 16384;
        const _Float16* qh = wb + 12 * 16384;
        const _Float16* ql = wb + 13 * 16384;
#pragma unroll
        for (int ks = 0; ks < 4; ++ks) {
            int ko = 32 * ks + 8 * hi4;
            f16x8 uh = ldf8(mh + ru * 128, ((ko * 2) ^ ((ru & 7) << 4)));
            f16x8 ul = ldf8(hrl + ru * 128, ((ko * 2) ^ ((ru & 7) << 4)));
#pragma unroll
            for (int j = 0; j < 4; ++j) {
                int n = 16 * (cb + j) + ln15;
                f16x8 bh = *(const f16x8*)(ph + n * 128 + ko);
                f16x8 bl = *(const f16x8*)(pl + n * 128 + ko);
                f32x4 a = acc4[j];
                a = MFMA16(uh, bh, a);
                a = MFMA16(uh, bl, a);
                a = MFMA16(ul, bh, a);
                acc4[j] = a;
            }
            f16x8 vh = ldf8(mh + rv * 128, ((ko * 2) ^ ((rv & 7) << 4)));
            f16x8 vl = ldf8(hrl + rv * 128, ((ko * 2) ^ ((rv & 7) << 4)));
#pragma unroll
            for (int j = 0; j < 4; ++j) {
                int n = 16 * (cb + j) + ln15;
                f16x8 bh = *(const f16x8*)(qh + n * 128 + ko);
                f16x8 bl = *(const f16x8*)(ql + n * 128 + ko);
                f32x4 a = acc4[j];
                a = MFMA16(vh, bh, a);
                a = MFMA16(vh, bl, a);
                a = MFMA16(vl, bh, a);
                acc4[j] = a;
            }
        }
        float dth[4];
#pragma unroll
        for (int q = 0; q < 4; ++q) {
            int bb = 16 * t + 4 * hi4 + q;
            dth[q] = theta[bu[bb]] - theta[bv[bb]];
        }
        float sums[4] = {0.f, 0.f, 0.f, 0.f};
#pragma unroll
        for (int j = 0; j < 4; ++j) {
            int ch = 16 * (cb + j) + ln15;
            float w256 = mlpW1[256 * HID + ch];
            float b1 = mlpb1[ch];
            float w2 = mlpW2[ch];
#pragma unroll
            for (int q = 0; q < 4; ++q)
                sums[q] += fmaxf(fmaf(dth[q], w256, acc4[j][q] + b1), 0.f) * w2;
        }
#pragma unroll
        for (int q = 0; q < 4; ++q) {
#pragma unroll
            for (int o = 1; o < 16; o <<= 1) sums[q] += __shfl_xor(sums[q], o, 16);
            if (ln15 == 0) atomicAdd(&red[16 * t + 4 * hi4 + q], sums[q]);
        }
    }
    __syncthreads();
    if (tid < NB) out[g * NB + tid] = red[tid] + mlpb2[0];
}

extern "C" void kernel_launch(void* const* d_in, const int* in_sizes, int n_in,
                              void* d_out, int out_size, void* d_ws, size_t ws_size,
                              hipStream_t stream) {
    const float* x          = (const float*)d_in[0];
    const int*   edge_index = (const int*)d_in[1];
    const int*   branch_u   = (const int*)d_in[2];
    const int*   branch_v   = (const int*)d_in[3];
    const float* Wp         = (const float*)d_in[4];
    const float* bp         = (const float*)d_in[5];
    const float* convW      = (const float*)d_in[6];
    const float* convb      = (const float*)d_in[7];
    const float* bn_gamma   = (const float*)d_in[8];
    const float* bn_beta    = (const float*)d_in[9];
    const float* bn_mean    = (const float*)d_in[10];
    const float* bn_var     = (const float*)d_in[11];
    const float* physW1     = (const float*)d_in[12];
    const float* physb1     = (const float*)d_in[13];
    const float* physW2     = (const float*)d_in[14];
    const float* physb2     = (const float*)d_in[15];
    const float* mlpW1      = (const float*)d_in[16];
    const float* mlpb1      = (const float*)d_in[17];
    const float* mlpW2      = (const float*)d_in[18];
    const float* mlpb2      = (const float*)d_in[19];
    float* out = (float*)d_out;

    _Float16* wb = (_Float16*)d_ws;                    // 466944 B
    float* fsc = (float*)((char*)d_ws + 466944);       // 5*128 floats
    float* fsh = fsc + 640;

    prep<<<459, 256, 0, stream>>>(convW, mlpW1, physW1, convb,
                                  bn_gamma, bn_beta, bn_mean, bn_var, wb, fsc, fsh);
    pinn_fused<<<NG, 512, 0, stream>>>(
        x, edge_index, branch_u, branch_v, Wp, bp,
        physb1, physW2, physb2, mlpW1, mlpb1, mlpW2, mlpb2,
        wb, fsc, fsh, out);
}